// Round 1
// 295.114 us; speedup vs baseline: 1.0770x; 1.0770x over previous
//
#include <hip/hip_runtime.h>

#define N_NODES 50000
#define N_EDGES 800000
#define D 128
#define N_LAYERS 3
#define OUT_F 16
#define N_GRAPHS 128
#define NBUCK 391            // ceil(50000/128) buckets of 128 nodes
#define EPB 4096             // edges per partition block
#define NB3 ((N_EDGES + EPB - 1) / EPB)  // 196
#define CAP 4096             // padded bucket capacity (mean 2048, sigma ~45)
#define NT32 ((N_NODES + 31) / 32)       // 1563 row-tiles of 32
#define NSL 8                            // column slices (16 cols each)
#define SLN ((size_t)N_NODES * 16)       // shorts per slice

typedef __attribute__((ext_vector_type(8))) short short8;
typedef __attribute__((ext_vector_type(16))) float floatx16;

__device__ __forceinline__ unsigned short f2bf(float f) {
  unsigned int u = __float_as_uint(f);
  u += 0x7fff + ((u >> 16) & 1);   // RNE
  return (unsigned short)(u >> 16);
}
__device__ __forceinline__ float bf2f(unsigned short b) {
  return __uint_as_float(((unsigned int)b) << 16);
}
__device__ __forceinline__ float blo(unsigned v) { return __uint_as_float(v << 16); }
__device__ __forceinline__ float bhi(unsigned v) { return __uint_as_float(v & 0xffff0000u); }

// ========== CSR build: padded-bucket counting sort (2 kernels) ==============
__global__ __launch_bounds__(256) void partition_kernel(
    const int* __restrict__ src, const int* __restrict__ dst,
    int* __restrict__ cursor, unsigned* __restrict__ pairs) {
  __shared__ unsigned pk[EPB];
  __shared__ int hist[NBUCK];
  __shared__ int wcur[NBUCK];
  const int e0 = blockIdx.x * EPB;
  const int n = min(EPB, N_EDGES - e0);
  const int t = threadIdx.x;
  for (int i = t; i < NBUCK; i += 256) hist[i] = 0;
  __syncthreads();
  for (int i = t; i < n; i += 256) {
    int d = dst[e0 + i], s = src[e0 + i];
    pk[i] = ((unsigned)d << 16) | (unsigned)s;
    atomicAdd(&hist[d >> 7], 1);
  }
  __syncthreads();
  for (int i = t; i < NBUCK; i += 256)
    wcur[i] = i * CAP + (hist[i] ? atomicAdd(&cursor[i], hist[i]) : 0);
  __syncthreads();
  for (int i = t; i < n; i += 256) {
    unsigned p = pk[i];
    int pos = atomicAdd(&wcur[p >> 23], 1);
    pairs[pos] = p;
  }
}

__global__ __launch_bounds__(256) void bucket_sort_kernel(
    const unsigned* __restrict__ pairs, const int* __restrict__ cursor,
    int* __restrict__ rowbeg, int* __restrict__ rowend, int* __restrict__ esrc) {
  __shared__ unsigned pk[CAP];
  __shared__ int sorted[CAP];
  __shared__ int hist[128], off[128], cur[128];
  const int bkt = blockIdx.x;
  const int t = threadIdx.x;
  const int beg = bkt * CAP;
  const int cnt = cursor[bkt];
  if (t < 128) hist[t] = 0;
  __syncthreads();
  for (int i = t; i < cnt; i += 256) {
    unsigned p = pairs[beg + i];
    pk[i] = p;
    atomicAdd(&hist[(p >> 16) & 127], 1);
  }
  __syncthreads();
  if (t < 128) off[t] = hist[t];
  __syncthreads();
  for (int o = 1; o < 128; o <<= 1) {
    int x = (t < 128 && t >= o) ? off[t - o] : 0;
    __syncthreads();
    if (t < 128) off[t] += x;
    __syncthreads();
  }
  if (t < 128) {
    int node = bkt * 128 + t;
    if (node < N_NODES) {
      rowbeg[node] = beg + off[t] - hist[t];
      rowend[node] = beg + off[t];
    }
    cur[t] = off[t] - hist[t];
  }
  __syncthreads();
  for (int i = t; i < cnt; i += 256) {
    unsigned p = pk[i];
    int pos = atomicAdd(&cur[(p >> 16) & 127], 1);
    sorted[pos] = (int)(p & 0xFFFFu);
  }
  __syncthreads();
  for (int i = t; i < cnt; i += 256) esrc[beg + i] = sorted[i];
}

// ========= prep: cast x -> bf16 SLICE-MAJOR [8][N][16]; weights -> frags ====
__global__ __launch_bounds__(256) void cast_x_kernel(
    const float* __restrict__ x, unsigned short* __restrict__ x16) {
  int i = blockIdx.x * 256 + threadIdx.x;     // one 8-col group per thread
  if (i >= N_NODES * 16) return;
  const int n = i >> 4, cg = i & 15;
  const float4 v0 = *(const float4*)&x[(size_t)n * D + cg * 8];
  const float4 v1 = *(const float4*)&x[(size_t)n * D + cg * 8 + 4];
  uint4 o;
  o.x = f2bf(v0.x) | ((unsigned)f2bf(v0.y) << 16);
  o.y = f2bf(v0.z) | ((unsigned)f2bf(v0.w) << 16);
  o.z = f2bf(v1.x) | ((unsigned)f2bf(v1.y) << 16);
  o.w = f2bf(v1.z) | ((unsigned)f2bf(v1.w) << 16);
  *(uint4*)&x16[(size_t)(cg >> 1) * SLN + (size_t)n * 16 + (cg & 1) * 8] = o;
}

// wt layout: [l][p:4][kst:32][lane:64][j:8] bf16 (p = phase = 32-col group).
// Element (lane,j) = B[kx][n], n = p*32+(lane&31), kx = kst*16+(lane>>5)*8+j;
// kx = seg*128+k, segs {rel_hi,rel_lo,root_hi,root_lo}. (Identical to the
// previous [half][nt] ordering since p == half*2+nt.)
__global__ __launch_bounds__(256) void prep_w_kernel(
    const float* __restrict__ Wrel, const float* __restrict__ Wroot,
    unsigned short* __restrict__ wt) {
  int idx = blockIdx.x * 256 + threadIdx.x;   // 3*2*2*32*64 = 24576 threads
  if (idx >= N_LAYERS * 2 * 2 * 32 * 64) return;
  const int lane = idx & 63;
  const int kst = (idx >> 6) & 31;
  const int nt = (idx >> 11) & 1;
  const int half = (idx >> 12) & 1;
  const int l = idx >> 13;
  const int n = half * 64 + nt * 32 + (lane & 31);
  const int kx0 = kst * 16 + (lane >> 5) * 8;
  const int seg = kx0 >> 7;           // same seg for all 8 j
  const int k0 = kx0 & 127;
  const int mat = seg >> 1, lo = seg & 1;
  const float* W = (mat ? Wroot : Wrel) + (size_t)l * D * D;
  unsigned short v[8];
#pragma unroll
  for (int j = 0; j < 8; ++j) {
    float w = W[(size_t)(k0 + j) * D + n];
    unsigned short hi = f2bf(w);
    v[j] = lo ? f2bf(w - bf2f(hi)) : hi;
  }
  unsigned short* dstp =
      wt + ((size_t)l * 128 + (half * 2 + nt) * 32 + kst) * 512 + lane * 8;
  *(uint4*)dstp = *(const uint4*)v;
}

// ===== aggregate: XCD-affine column slices. blockIdx&7 = slice = XCD; =======
// each XCD gathers only its 1.6 MB h-slice -> per-XCD L2 resident.
// block = one bucket (128 nodes) x one slice; 2 lanes/node x 16 B.
__global__ __launch_bounds__(256) void agg_kernel(
    const unsigned short* __restrict__ h,
    const int* __restrict__ rowbeg, const int* __restrict__ rowend,
    const int* __restrict__ esrc, unsigned short* __restrict__ agg) {
  __shared__ int sE[CAP];               // staged edge sources for this bucket
  const int bid = blockIdx.x;
  const int slice = bid & 7;            // round-robin dispatch -> XCD id
  const int bkt = bid >> 3;
  const int t = threadIdx.x;
  const int ebase = bkt * CAP;
  const int lastn = min(bkt * 128 + 127, N_NODES - 1);
  const int cnt = rowend[lastn] - ebase;
  for (int i = t; i < cnt; i += 256) sE[i] = esrc[ebase + i];
  __syncthreads();
  const int n = bkt * 128 + (t >> 1);
  if (n >= N_NODES) return;
  const int lane = t & 1;
  const unsigned short* hs = h + (size_t)slice * SLN + lane * 8;
  int e = rowbeg[n] - ebase;
  const int end = rowend[n] - ebase;
  float a0 = 0, a1 = 0, a2 = 0, a3 = 0, a4 = 0, a5 = 0, a6 = 0, a7 = 0;
  for (; e + 4 <= end; e += 4) {
    const uint4 v0 = *(const uint4*)&hs[(size_t)sE[e] * 16];
    const uint4 v1 = *(const uint4*)&hs[(size_t)sE[e + 1] * 16];
    const uint4 v2 = *(const uint4*)&hs[(size_t)sE[e + 2] * 16];
    const uint4 v3 = *(const uint4*)&hs[(size_t)sE[e + 3] * 16];
    a0 += blo(v0.x) + blo(v1.x) + blo(v2.x) + blo(v3.x);
    a1 += bhi(v0.x) + bhi(v1.x) + bhi(v2.x) + bhi(v3.x);
    a2 += blo(v0.y) + blo(v1.y) + blo(v2.y) + blo(v3.y);
    a3 += bhi(v0.y) + bhi(v1.y) + bhi(v2.y) + bhi(v3.y);
    a4 += blo(v0.z) + blo(v1.z) + blo(v2.z) + blo(v3.z);
    a5 += bhi(v0.z) + bhi(v1.z) + bhi(v2.z) + bhi(v3.z);
    a6 += blo(v0.w) + blo(v1.w) + blo(v2.w) + blo(v3.w);
    a7 += bhi(v0.w) + bhi(v1.w) + bhi(v2.w) + bhi(v3.w);
  }
  for (; e < end; ++e) {
    const uint4 v0 = *(const uint4*)&hs[(size_t)sE[e] * 16];
    a0 += blo(v0.x); a1 += bhi(v0.x);
    a2 += blo(v0.y); a3 += bhi(v0.y);
    a4 += blo(v0.z); a5 += bhi(v0.z);
    a6 += blo(v0.w); a7 += bhi(v0.w);
  }
  uint4 o;
  o.x = f2bf(a0) | ((unsigned)f2bf(a1) << 16);
  o.y = f2bf(a2) | ((unsigned)f2bf(a3) << 16);
  o.z = f2bf(a4) | ((unsigned)f2bf(a5) << 16);
  o.w = f2bf(a6) | ((unsigned)f2bf(a7) << 16);
  *(uint4*)&agg[(size_t)slice * SLN + (size_t)n * 16 + lane * 8] = o;
}

// ====== MFMA 32x32x16 GEMM: 1 tile/wave, all 128 cols, B phased in LDS ======
// grid = 512 blocks x 4 waves = 2048 tile slots (1563 used, rest barrier-only).
// A (agg+hv frags) loaded ONCE as contiguous 1KB wave-loads (slice layout),
// held in registers across 4 phases; each phase stages 32KB of B (32 cols).
__global__ __launch_bounds__(256, 2) void gemm32_kernel(
    const unsigned short* __restrict__ agg, const unsigned short* __restrict__ hv,
    const unsigned short* __restrict__ wt, const float* __restrict__ brel,
    unsigned short* __restrict__ outp) {
  __shared__ unsigned short blds[16384];   // 32 KB: one phase's 32 frag-sets
  const int t = threadIdx.x;
  const int wave = t >> 6, lane = t & 63;
  const int tile = blockIdx.x * 4 + wave;
  const int r_lane = lane & 31, hseg = lane >> 5;
  const int r0 = tile * 32;
  int arow = r0 + r_lane;
  if (arow >= N_NODES) arow = N_NODES - 1;
  short8 ag[8], hh[8];
#pragma unroll
  for (int i = 0; i < 8; ++i) {
    const size_t off = (size_t)i * SLN + (size_t)arow * 16 + hseg * 8;
    ag[i] = *(const short8*)&agg[off];
    hh[i] = *(const short8*)&hv[off];
  }
#pragma unroll
  for (int p = 0; p < 4; ++p) {
    __syncthreads();                     // prev-phase reads done before restage
    const unsigned short* ws = wt + (size_t)p * 32 * 512;
#pragma unroll
    for (int j = 0; j < 8; ++j) {
      const int idx = t + j * 256;       // 2048 uint4 units = 32 KB
      *(uint4*)&blds[idx * 8] = *(const uint4*)&ws[idx * 8];
    }
    __syncthreads();
    floatx16 accA = {0.f}, accB = {0.f}; // rel-chain, root-chain (independent)
#pragma unroll
    for (int k = 0; k < 16; ++k) {
      const short8 b0 = *(const short8*)&blds[(size_t)k * 512 + lane * 8];
      const short8 b1 = *(const short8*)&blds[(size_t)(16 + k) * 512 + lane * 8];
      accA = __builtin_amdgcn_mfma_f32_32x32x16_bf16(ag[k & 7], b0, accA, 0, 0, 0);
      accB = __builtin_amdgcn_mfma_f32_32x32x16_bf16(hh[k & 7], b1, accB, 0, 0, 0);
    }
    const int cb = p * 32 + r_lane;
    const float bias = brel[cb];
    const size_t cbase = (size_t)(cb >> 4) * SLN + (cb & 15);
#pragma unroll
    for (int reg = 0; reg < 16; ++reg) {
      const int row = r0 + (reg & 3) + 8 * (reg >> 2) + 4 * hseg;
      if (row < N_NODES)
        outp[cbase + (size_t)row * 16] =
            f2bf(fmaxf(accA[reg] + accB[reg] + bias, 0.f));
    }
  }
}

// ============= pool (segment ranges; batch sorted) + MLP head ===============
__device__ __forceinline__ int lb_search(const int* __restrict__ a, int n, int key) {
  int lo = 0, hi = n;
  while (lo < hi) {
    int m = (lo + hi) >> 1;
    if (a[m] < key) lo = m + 1; else hi = m;
  }
  return lo;
}

__global__ __launch_bounds__(256) void pool_head_kernel(
    const unsigned short* __restrict__ h, const int* __restrict__ batch,
    const float* __restrict__ W1, const float* __restrict__ b1,
    const float* __restrict__ W2, const float* __restrict__ b2,
    float* __restrict__ out) {
  __shared__ float sums_lds[16][128];
  __shared__ float pooled[128];
  __shared__ float hidden[128];
  __shared__ int range[2];
  const int g = blockIdx.x;
  const int t = threadIdx.x;
  if (t < 2) range[t] = lb_search(batch, N_NODES, g + t);
  __syncthreads();
  const int lo = range[0], hi = range[1];
  const int rg = t >> 4, cg = t & 15;
  float a0 = 0, a1 = 0, a2 = 0, a3 = 0, a4 = 0, a5 = 0, a6 = 0, a7 = 0;
  for (int n = lo + rg; n < hi; n += 16) {
    const uint4 v = *(const uint4*)
        &h[(size_t)(cg >> 1) * SLN + (size_t)n * 16 + (cg & 1) * 8];
    a0 += blo(v.x); a1 += bhi(v.x);
    a2 += blo(v.y); a3 += bhi(v.y);
    a4 += blo(v.z); a5 += bhi(v.z);
    a6 += blo(v.w); a7 += bhi(v.w);
  }
  sums_lds[rg][cg * 8 + 0] = a0; sums_lds[rg][cg * 8 + 1] = a1;
  sums_lds[rg][cg * 8 + 2] = a2; sums_lds[rg][cg * 8 + 3] = a3;
  sums_lds[rg][cg * 8 + 4] = a4; sums_lds[rg][cg * 8 + 5] = a5;
  sums_lds[rg][cg * 8 + 6] = a6; sums_lds[rg][cg * 8 + 7] = a7;
  __syncthreads();
  if (t < 128) {
    float s = 0.f;
#pragma unroll
    for (int r = 0; r < 16; ++r) s += sums_lds[r][t];
    pooled[t] = s / fmaxf((float)(hi - lo), 1.f);
  }
  __syncthreads();
  if (t < 128) {
    float a = b1[t];
    for (int k = 0; k < D; ++k) a += pooled[k] * W1[k * D + t];
    hidden[t] = a;
  }
  __syncthreads();
  if (t < OUT_F) {
    float o = b2[t];
    for (int k = 0; k < D; ++k) o += hidden[k] * W2[k * OUT_F + t];
    out[(size_t)g * OUT_F + t] = o;
  }
}

// ============================== launch ======================================
extern "C" void kernel_launch(void* const* d_in, const int* in_sizes, int n_in,
                              void* d_out, int out_size, void* d_ws, size_t ws_size,
                              hipStream_t stream) {
  const float* x     = (const float*)d_in[0];
  const int*   ei    = (const int*)d_in[1];
  const int*   batch = (const int*)d_in[2];
  const float* Wrel  = (const float*)d_in[3];
  const float* brel  = (const float*)d_in[4];
  const float* Wroot = (const float*)d_in[5];
  const float* W1    = (const float*)d_in[6];
  const float* b1    = (const float*)d_in[7];
  const float* W2    = (const float*)d_in[8];
  const float* b2    = (const float*)d_in[9];
  float* out = (float*)d_out;

  const size_t ND = (size_t)N_NODES * D;
  unsigned short* bufA = (unsigned short*)d_ws;            // N*D bf16 (slice-major)
  unsigned short* bufB = bufA + ND;                        // N*D bf16
  unsigned short* bufC = bufB + ND;                        // N*D bf16 (x16)
  unsigned short* wt   = bufC + ND;                        // 3*128*512 bf16
  int* rowbeg = (int*)(wt + (size_t)N_LAYERS * 128 * 512); // N
  int* rowend = rowbeg + N_NODES;                          // N
  int* esrc   = rowend + N_NODES;                          // NBUCK*CAP
  unsigned* pairs = (unsigned*)(esrc + (size_t)NBUCK * CAP);  // NBUCK*CAP
  int* cursor = (int*)(pairs + (size_t)NBUCK * CAP);       // NBUCK

  const int* esrc_in = ei;
  const int* edst_in = ei + N_EDGES;

  // ---- CSR build (padded buckets, 2 kernels) ----
  hipMemsetAsync(cursor, 0, NBUCK * sizeof(int), stream);
  partition_kernel<<<NB3, 256, 0, stream>>>(esrc_in, edst_in, cursor, pairs);
  bucket_sort_kernel<<<NBUCK, 256, 0, stream>>>(pairs, cursor, rowbeg, rowend, esrc);

  // ---- prep bf16 ----
  cast_x_kernel<<<(N_NODES * 16 + 255) / 256, 256, 0, stream>>>(x, bufC);
  prep_w_kernel<<<(N_LAYERS * 2 * 2 * 32 * 64 + 255) / 256, 256, 0, stream>>>(
      Wrel, Wroot, wt);

  // ---- 3 layers (agg + gemm, out-of-place rotation) ----
  const int agg_blocks = NBUCK * 8;                    // 3128, slice = bid&7
  const size_t WL = (size_t)128 * 512;
  // l0: agg(x16=bufC)->bufA ; gemm(bufA,bufC)->bufB
  agg_kernel<<<agg_blocks, 256, 0, stream>>>(bufC, rowbeg, rowend, esrc, bufA);
  gemm32_kernel<<<512, 256, 0, stream>>>(bufA, bufC, wt, brel, bufB);
  // l1: agg(bufB)->bufA ; gemm(bufA,bufB)->bufC
  agg_kernel<<<agg_blocks, 256, 0, stream>>>(bufB, rowbeg, rowend, esrc, bufA);
  gemm32_kernel<<<512, 256, 0, stream>>>(bufA, bufB, wt + WL, brel + D, bufC);
  // l2: agg(bufC)->bufB ; gemm(bufB,bufC)->bufA
  agg_kernel<<<agg_blocks, 256, 0, stream>>>(bufC, rowbeg, rowend, esrc, bufB);
  gemm32_kernel<<<512, 256, 0, stream>>>(bufB, bufC, wt + 2 * WL, brel + 2 * D, bufA);

  pool_head_kernel<<<N_GRAPHS, 256, 0, stream>>>(bufA, batch, W1, b1, W2, b2, out);
}